// Round 1
// baseline (698.428 us; speedup 1.0000x reference)
//
#include <hip/hip_runtime.h>
#include <stdint.h>

#define NVOX 400000
#define KTAPS 27
// CIN = COUT = 64

typedef __bf16 bf16x8 __attribute__((ext_vector_type(8)));
typedef float floatx16 __attribute__((ext_vector_type(16)));

__device__ __forceinline__ uint32_t f2bf(float f) {
  // round-to-nearest-even fp32 -> bf16 (inputs are finite; no NaN handling)
  uint32_t u = __builtin_bit_cast(uint32_t, f);
  u += 0x7fffu + ((u >> 16) & 1u);
  return u >> 16;
}

__device__ __forceinline__ floatx16 zero16() {
  floatx16 z = {0.f,0.f,0.f,0.f,0.f,0.f,0.f,0.f,
                0.f,0.f,0.f,0.f,0.f,0.f,0.f,0.f};
  return z;
}

// Weight convert + transpose: Wt[k][co][ci] = bf16(W[k][ci][co]).
// Exact grid: 27*64*64 / 256 = 432 blocks.
__global__ void k_wt(const float* __restrict__ W, unsigned short* __restrict__ Wt) {
  int i = blockIdx.x * 256 + threadIdx.x;
  int k = i >> 12;          // /4096
  int rem = i & 4095;
  int ci = rem >> 6;
  int co = rem & 63;
  Wt[(k << 12) + (co << 6) + ci] = (unsigned short)f2bf(W[i]);
}

// Feats convert: bf16 copy of feats. Exact grid: 400000*64/4/256 = 25000 blocks.
__global__ void k_feats(const float4* __restrict__ F, uint2* __restrict__ Fb) {
  int i = blockIdx.x * 256 + threadIdx.x;
  float4 v = F[i];
  uint2 o;
  o.x = f2bf(v.x) | (f2bf(v.y) << 16);
  o.y = f2bf(v.z) | (f2bf(v.w) << 16);
  Fb[i] = o;
}

// Main kernel: block = 256 threads = 4 waves; tile = 256 voxels x 64 couts.
// Wave w owns voxels [w*64, w*64+64): 2 M-tiles of 32 x 2 N-tiles of 32,
// mfma_f32_32x32x16_bf16, K-loop = 27 taps x 4 chunks of 16 channels.
// LDS rows padded to 72 bf16 (144 B) for balanced b128 bank access.
template<bool FB>
__global__ __launch_bounds__(256) void k_conv(
    const float* __restrict__ feats,         // fp32 feats (fallback path)
    const unsigned short* __restrict__ featsb, // bf16 feats (fast path)
    const unsigned short* __restrict__ Wt,   // bf16 W transposed [k][co][ci]
    const float* __restrict__ bias,
    const int* __restrict__ nbr,             // [27][NVOX]
    float* __restrict__ out) {               // [NVOX][64]

  __shared__ alignas(16) unsigned short lA[256 * 72]; // 36864 B
  __shared__ alignas(16) unsigned short lB[64 * 72];  //  9216 B

  const int t = threadIdx.x;
  const int w = t >> 6;         // wave 0..3
  const int l = t & 63;         // lane
  const int half = l >> 5;      // 0/1: which k-half of the fragment
  const int lm = l & 31;        // m (or n) index within 32-tile
  const int v0 = blockIdx.x * 256;

  floatx16 acc00 = zero16(), acc01 = zero16(), acc10 = zero16(), acc11 = zero16();

  // Fragment read pointers (elements). A row = local voxel; B row = cout.
  const unsigned short* pA0 = &lA[(w * 64 + lm) * 72 + half * 8];
  const unsigned short* pA1 = pA0 + 32 * 72;
  const unsigned short* pB0 = &lB[lm * 72 + half * 8];
  const unsigned short* pB1 = pB0 + 32 * 72;

  const int rr = t >> 3;  // staging row 0..31 (per pass)
  const int cc = t & 7;   // 16 B chunk within a 128 B feat row

#pragma unroll 1
  for (int k = 0; k < KTAPS; ++k) {
    __syncthreads();  // previous iteration's LDS reads done

    // ---- stage B: copy Wt[k] (4096 bf16) into padded lB ----
    {
      const unsigned short* src = Wt + (k << 12) + (t >> 2) * 64 + (t & 3) * 16;
      uint4 d0 = *(const uint4*)src;
      uint4 d1 = *(const uint4*)(src + 8);
      unsigned short* dst = &lB[(t >> 2) * 72 + (t & 3) * 16];
      *(uint4*)dst = d0;
      *(uint4*)(dst + 8) = d1;
    }

    // ---- stage A: gather 256 voxel rows (8 passes x 32 rows) ----
#pragma unroll
    for (int p = 0; p < 8; ++p) {
      int r = p * 32 + rr;
      int vg = v0 + r;
      int idx = (vg < NVOX) ? nbr[k * NVOX + vg] : -1;
      unsigned short* dst = &lA[r * 72 + cc * 8];
      if (idx >= 0) {
        if (FB) {
          *(uint4*)dst = *(const uint4*)(featsb + (size_t)idx * 64 + cc * 8);
        } else {
          const float* s = feats + (size_t)idx * 64 + cc * 8;
          float4 f0 = *(const float4*)s;
          float4 f1 = *(const float4*)(s + 4);
          uint4 d;
          d.x = f2bf(f0.x) | (f2bf(f0.y) << 16);
          d.y = f2bf(f0.z) | (f2bf(f0.w) << 16);
          d.z = f2bf(f1.x) | (f2bf(f1.y) << 16);
          d.w = f2bf(f1.z) | (f2bf(f1.w) << 16);
          *(uint4*)dst = d;
        }
      } else {
        uint4 z = {0u, 0u, 0u, 0u};
        *(uint4*)dst = z;
      }
    }
    __syncthreads();

    // ---- MFMA: 4 K-chunks of 16 channels ----
#pragma unroll
    for (int kc = 0; kc < 4; ++kc) {
      bf16x8 a0 = *(const bf16x8*)(pA0 + kc * 16);
      bf16x8 a1 = *(const bf16x8*)(pA1 + kc * 16);
      bf16x8 b0 = *(const bf16x8*)(pB0 + kc * 16);
      bf16x8 b1 = *(const bf16x8*)(pB1 + kc * 16);
      acc00 = __builtin_amdgcn_mfma_f32_32x32x16_bf16(a0, b0, acc00, 0, 0, 0);
      acc01 = __builtin_amdgcn_mfma_f32_32x32x16_bf16(a0, b1, acc01, 0, 0, 0);
      acc10 = __builtin_amdgcn_mfma_f32_32x32x16_bf16(a1, b0, acc10, 0, 0, 0);
      acc11 = __builtin_amdgcn_mfma_f32_32x32x16_bf16(a1, b1, acc11, 0, 0, 0);
    }
  }

  // ---- epilogue: C/D layout col=lane&31 (cout), row=(reg&3)+8*(reg>>2)+4*half ----
  float bv0 = bias[lm];
  float bv1 = bias[32 + lm];
#pragma unroll
  for (int reg = 0; reg < 16; ++reg) {
    int m = (reg & 3) + 8 * (reg >> 2) + 4 * half;
    int vm0 = v0 + w * 64 + m;
    int vm1 = vm0 + 32;
    if (vm0 < NVOX) {
      out[vm0 * 64 + lm]      = acc00[reg] + bv0;
      out[vm0 * 64 + 32 + lm] = acc01[reg] + bv1;
    }
    if (vm1 < NVOX) {
      out[vm1 * 64 + lm]      = acc10[reg] + bv0;
      out[vm1 * 64 + 32 + lm] = acc11[reg] + bv1;
    }
  }
}

extern "C" void kernel_launch(void* const* d_in, const int* in_sizes, int n_in,
                              void* d_out, int out_size, void* d_ws, size_t ws_size,
                              hipStream_t stream) {
  const float* feats  = (const float*)d_in[0];
  const float* weight = (const float*)d_in[1];
  const float* bias   = (const float*)d_in[2];
  const int*   nbr    = (const int*)d_in[3];
  float* out = (float*)d_out;

  unsigned short* Wt = (unsigned short*)d_ws;
  const size_t featsOff = 256 * 1024;                    // Wt needs 221184 B
  const size_t fbytes = (size_t)NVOX * 64 * 2;           // 51.2 MB
  const bool bigws = ws_size >= featsOff + fbytes;       // constant per session -> graph-safe

  k_wt<<<432, 256, 0, stream>>>(weight, Wt);

  const int grid = (NVOX + 255) / 256;  // 1563
  if (bigws) {
    unsigned short* Fb = (unsigned short*)((char*)d_ws + featsOff);
    k_feats<<<25000, 256, 0, stream>>>((const float4*)feats, (uint2*)Fb);
    k_conv<true><<<grid, 256, 0, stream>>>(feats, Fb, Wt, bias, nbr, out);
  } else {
    k_conv<false><<<grid, 256, 0, stream>>>(feats, nullptr, Wt, bias, nbr, out);
  }
}

// Round 2
// 358.151 us; speedup vs baseline: 1.9501x; 1.9501x over previous
//
#include <hip/hip_runtime.h>
#include <stdint.h>

#define NVOX 400000
#define KTAPS 27
// CIN = COUT = 64

typedef __bf16 bf16x8 __attribute__((ext_vector_type(8)));
typedef float floatx16 __attribute__((ext_vector_type(16)));

__device__ __forceinline__ uint32_t f2bf(float f) {
  uint32_t u = __builtin_bit_cast(uint32_t, f);
  u += 0x7fffu + ((u >> 16) & 1u);
  return u >> 16;
}

__device__ __forceinline__ floatx16 zero16() {
  floatx16 z = {0.f,0.f,0.f,0.f,0.f,0.f,0.f,0.f,
                0.f,0.f,0.f,0.f,0.f,0.f,0.f,0.f};
  return z;
}

// Weight convert + transpose: Wt[k][co][ci] = bf16(W[k][ci][co]). 432 blocks.
__global__ void k_wt(const float* __restrict__ W, unsigned short* __restrict__ Wt) {
  int i = blockIdx.x * 256 + threadIdx.x;
  int k = i >> 12;
  int rem = i & 4095;
  int ci = rem >> 6;
  int co = rem & 63;
  Wt[(k << 12) + (co << 6) + ci] = (unsigned short)f2bf(W[i]);
}

// Feats convert: fp32 -> bf16, 4 float4 per thread. Grid 6250 blocks.
__global__ void k_feats(const float4* __restrict__ F, uint2* __restrict__ Fb) {
  int i0 = blockIdx.x * 1024 + threadIdx.x;
#pragma unroll
  for (int j = 0; j < 4; ++j) {
    int i = i0 + j * 256;
    float4 v = F[i];
    uint2 o;
    o.x = f2bf(v.x) | (f2bf(v.y) << 16);
    o.y = f2bf(v.z) | (f2bf(v.w) << 16);
    Fb[i] = o;
  }
}

// Main kernel: block = 256 threads = 4 waves; tile = 256 voxels x 64 couts.
// Software-pipelined: during tap k's MFMA phase we prefetch tap k+1's
// gathered A rows + B tile into registers and tap k+2's indices.
// LDS rows padded to 72 bf16 (144 B) — measured 0 bank conflicts (R1).
template<bool FB>
__global__ __launch_bounds__(256, 3) void k_conv(
    const float* __restrict__ feats,
    const unsigned short* __restrict__ featsb,
    const unsigned short* __restrict__ Wt,     // [k][co][ci] bf16
    const float* __restrict__ bias,
    const int* __restrict__ nbr,               // [27][NVOX]
    float* __restrict__ out) {                 // [NVOX][64]

  __shared__ alignas(16) unsigned short lA[256 * 72]; // 36864 B
  __shared__ alignas(16) unsigned short lB[64 * 72];  //  9216 B

  const int t = threadIdx.x;
  const int w = t >> 6;
  const int l = t & 63;
  const int half = l >> 5;
  const int lm = l & 31;
  const int v0 = blockIdx.x * 256;

  floatx16 acc00 = zero16(), acc01 = zero16(), acc10 = zero16(), acc11 = zero16();

  const unsigned short* pA0 = &lA[(w * 64 + lm) * 72 + half * 8];
  const unsigned short* pA1 = pA0 + 32 * 72;
  const unsigned short* pB0 = &lB[lm * 72 + half * 8];
  const unsigned short* pB1 = pB0 + 32 * 72;

  const int rr = t >> 3;   // staging row within a 32-row pass
  const int cc = t & 7;    // 16 B chunk within a 128 B feat row

  // Per-thread staging geometry (constant across taps)
  int voff[8];
  bool vld[8];
#pragma unroll
  for (int p = 0; p < 8; ++p) {
    voff[p] = v0 + p * 32 + rr;
    vld[p] = voff[p] < NVOX;
  }
  const int brow = t >> 2;          // B staging row (cout)
  const int bcol = (t & 3) * 16;    // B staging col (ci)

  // ---- pipeline registers ----
  int idxA[8];   // indices for rows currently held in rA
  int idxN[8];   // indices for the next tap (gather addresses)
  uint4 rA[8];
  uint4 rB0, rB1;

  auto gather = [&](int id) -> uint4 {
    int sid = id < 0 ? 0 : id;
    if (FB) {
      return *(const uint4*)(featsb + (size_t)sid * 64 + cc * 8);
    } else {
      const float* s = feats + (size_t)sid * 64 + cc * 8;
      float4 f0 = *(const float4*)s;
      float4 f1 = *(const float4*)(s + 4);
      uint4 d;
      d.x = f2bf(f0.x) | (f2bf(f0.y) << 16);
      d.y = f2bf(f0.z) | (f2bf(f0.w) << 16);
      d.z = f2bf(f1.x) | (f2bf(f1.y) << 16);
      d.w = f2bf(f1.z) | (f2bf(f1.w) << 16);
      return d;
    }
  };

  // ---- prologue: indices tap0 -> gather tap0 + B tap0 -> indices tap1 ----
#pragma unroll
  for (int p = 0; p < 8; ++p) idxN[p] = vld[p] ? nbr[voff[p]] : -1;
  {
    const unsigned short* src = Wt + brow * 64 + bcol;
    rB0 = *(const uint4*)src;
    rB1 = *(const uint4*)(src + 8);
  }
#pragma unroll
  for (int p = 0; p < 8; ++p) {
    int id = idxN[p];
    idxA[p] = id;
    rA[p] = gather(id);
  }
#pragma unroll
  for (int p = 0; p < 8; ++p) idxN[p] = vld[p] ? nbr[NVOX + voff[p]] : -1;

#pragma unroll 1
  for (int k = 0; k < KTAPS; ++k) {
    __syncthreads();   // previous tap's LDS reads done

    // ---- write phase: registers -> LDS (zero-mask invalid rows here) ----
#pragma unroll
    for (int p = 0; p < 8; ++p) {
      uint4 v = rA[p];
      if (idxA[p] < 0) { v.x = 0u; v.y = 0u; v.z = 0u; v.w = 0u; }
      *(uint4*)&lA[(p * 32 + rr) * 72 + cc * 8] = v;
    }
    {
      unsigned short* dst = &lB[brow * 72 + bcol];
      *(uint4*)dst = rB0;
      *(uint4*)(dst + 8) = rB1;
    }
    __syncthreads();   // LDS tiles ready

    // ---- prefetch phase for tap k+1 (overlaps the MFMA phase below) ----
    if (k + 1 < KTAPS) {
      const unsigned short* src = Wt + ((k + 1) << 12) + brow * 64 + bcol;
      rB0 = *(const uint4*)src;
      rB1 = *(const uint4*)(src + 8);
#pragma unroll
      for (int p = 0; p < 8; ++p) {
        int id = idxN[p];
        idxA[p] = id;
        rA[p] = gather(id);
      }
      if (k + 2 < KTAPS) {
        const int* nb = nbr + (size_t)(k + 2) * NVOX;
#pragma unroll
        for (int p = 0; p < 8; ++p) idxN[p] = vld[p] ? nb[voff[p]] : -1;
      }
    }

    // ---- MFMA phase: 4 K-chunks of 16 channels ----
#pragma unroll
    for (int kc = 0; kc < 4; ++kc) {
      bf16x8 a0 = *(const bf16x8*)(pA0 + kc * 16);
      bf16x8 a1 = *(const bf16x8*)(pA1 + kc * 16);
      bf16x8 b0 = *(const bf16x8*)(pB0 + kc * 16);
      bf16x8 b1 = *(const bf16x8*)(pB1 + kc * 16);
      acc00 = __builtin_amdgcn_mfma_f32_32x32x16_bf16(a0, b0, acc00, 0, 0, 0);
      acc01 = __builtin_amdgcn_mfma_f32_32x32x16_bf16(a0, b1, acc01, 0, 0, 0);
      acc10 = __builtin_amdgcn_mfma_f32_32x32x16_bf16(a1, b0, acc10, 0, 0, 0);
      acc11 = __builtin_amdgcn_mfma_f32_32x32x16_bf16(a1, b1, acc11, 0, 0, 0);
    }
  }

  // ---- epilogue: C/D layout col=lane&31 (cout), row=(reg&3)+8*(reg>>2)+4*half ----
  float bv0 = bias[lm];
  float bv1 = bias[32 + lm];
#pragma unroll
  for (int reg = 0; reg < 16; ++reg) {
    int m = (reg & 3) + 8 * (reg >> 2) + 4 * half;
    int vm0 = v0 + w * 64 + m;
    int vm1 = vm0 + 32;
    if (vm0 < NVOX) {
      out[vm0 * 64 + lm]      = acc00[reg] + bv0;
      out[vm0 * 64 + 32 + lm] = acc01[reg] + bv1;
    }
    if (vm1 < NVOX) {
      out[vm1 * 64 + lm]      = acc10[reg] + bv0;
      out[vm1 * 64 + 32 + lm] = acc11[reg] + bv1;
    }
  }
}

extern "C" void kernel_launch(void* const* d_in, const int* in_sizes, int n_in,
                              void* d_out, int out_size, void* d_ws, size_t ws_size,
                              hipStream_t stream) {
  const float* feats  = (const float*)d_in[0];
  const float* weight = (const float*)d_in[1];
  const float* bias   = (const float*)d_in[2];
  const int*   nbr    = (const int*)d_in[3];
  float* out = (float*)d_out;

  unsigned short* Wt = (unsigned short*)d_ws;
  const size_t featsOff = 256 * 1024;
  const size_t fbytes = (size_t)NVOX * 64 * 2;
  const bool bigws = ws_size >= featsOff + fbytes;

  k_wt<<<432, 256, 0, stream>>>(weight, Wt);

  const int grid = (NVOX + 255) / 256;  // 1563
  if (bigws) {
    unsigned short* Fb = (unsigned short*)((char*)d_ws + featsOff);
    k_feats<<<6250, 256, 0, stream>>>((const float4*)feats, (uint2*)Fb);
    k_conv<true><<<grid, 256, 0, stream>>>(feats, Fb, Wt, bias, nbr, out);
  } else {
    k_conv<false><<<grid, 256, 0, stream>>>(feats, nullptr, Wt, bias, nbr, out);
  }
}